// Round 6
// baseline (96.344 us; speedup 1.0000x reference)
//
#include <hip/hip_runtime.h>
#include <hip/hip_bf16.h>

#define NR 8192
#define DIM 512

typedef __attribute__((ext_vector_type(8))) short bf16x8;
typedef __attribute__((ext_vector_type(4))) float f32x4;

__device__ static inline void gload_lds16(const void* g, void* l) {
    __builtin_amdgcn_global_load_lds(
        (const __attribute__((address_space(1))) void*)g,
        (__attribute__((address_space(3))) void*)l, 16, 0, 0);
}

// One block (256 threads) per row: compute |im|^2, |s|^2, im.s in one pass,
// write bf16-normalized rows + fp32 diag. Block 0 also zeroes the accumulator.
__global__ __launch_bounds__(256) void normalize_kernel(
    const float* __restrict__ im, const float* __restrict__ s,
    __hip_bfloat16* __restrict__ im_n, __hip_bfloat16* __restrict__ s_n,
    float* __restrict__ diag, double* __restrict__ acc)
{
    const int row = blockIdx.x;
    const int t = threadIdx.x;
    if (row == 0 && t == 0) acc[0] = 0.0;

    const float2* imr = (const float2*)(im + (size_t)row * DIM);
    const float2* sr  = (const float2*)(s  + (size_t)row * DIM);
    float2 iv = imr[t];
    float2 sv = sr[t];

    float sim = iv.x * iv.x + iv.y * iv.y;
    float sss = sv.x * sv.x + sv.y * sv.y;
    float sd  = iv.x * sv.x + iv.y * sv.y;

    #pragma unroll
    for (int off = 32; off; off >>= 1) {
        sim += __shfl_down(sim, off);
        sss += __shfl_down(sss, off);
        sd  += __shfl_down(sd, off);
    }

    __shared__ float red[3][4];
    const int wid = t >> 6, lane = t & 63;
    if (lane == 0) { red[0][wid] = sim; red[1][wid] = sss; red[2][wid] = sd; }
    __syncthreads();
    sim = red[0][0] + red[0][1] + red[0][2] + red[0][3];
    sss = red[1][0] + red[1][1] + red[1][2] + red[1][3];
    sd  = red[2][0] + red[2][1] + red[2][2] + red[2][3];

    const float ri = rsqrtf(sim);
    const float rs = rsqrtf(sss);
    if (t == 0) diag[row] = sd * ri * rs;

    __hip_bfloat162* io = (__hip_bfloat162*)(im_n + (size_t)row * DIM);
    __hip_bfloat162* so = (__hip_bfloat162*)(s_n  + (size_t)row * DIM);
    __hip_bfloat162 a, b;
    a.x = __float2bfloat16(iv.x * ri); a.y = __float2bfloat16(iv.y * ri);
    b.x = __float2bfloat16(sv.x * rs); b.y = __float2bfloat16(sv.y * rs);
    io[t] = a;
    so[t] = b;
}

// 256x256 tile, BK=64, 8 waves (2M x 4N), double-buffered LDS (128 KiB).
// 4 phases per K-tile: {stage half-tile + ds_reads -> s_waitcnt vmcnt(4)
// -> s_barrier -> setprio(1) 16xMFMA setprio(0) -> s_barrier}. NO manual
// lgkmcnt fences: the compiler emits fine-grained lgkmcnt between ds_read
// and MFMA, letting each wave start MFMAs as soon as its first fragments
// return instead of draining all phase reads (the R3 laggard-serializer).
// vmcnt never drained to 0 in the main loop (proven R3 ledger: each drain
// targets loads issued 2 phases earlier). B-half0 frags held p1 -> p4.
__global__ __launch_bounds__(512, 2) void gemm_loss_kernel(
    const __hip_bfloat16* __restrict__ A,
    const __hip_bfloat16* __restrict__ B,
    const float* __restrict__ diag,
    double* __restrict__ acc_out)
{
    __shared__ char Asm[2][32768];   // [buf][256 rows][128 B]
    __shared__ char Bsm[2][32768];

    const int tid  = threadIdx.x;
    const int l    = tid & 63;
    const int w    = tid >> 6;          // wave 0..7
    const int wm   = w >> 2;            // 0..1
    const int wn   = w & 3;             // 0..3
    const int bm = blockIdx.y, bn = blockIdx.x;

    const int lr = l >> 3;              // 0..7 row within 8-row group
    const int ls = l & 7;               // 0..7 16B slot
    const int csw = ls ^ lr;            // swizzled content chunk for staging

    const int frow = l & 15;            // fragment lane row
    const int fc   = l >> 4;            // 0..3 k-chunk

    const char* Agb = (const char*)A + (size_t)bm * 256 * (DIM * 2);
    const char* Bgb = (const char*)B + (size_t)bn * 256 * (DIM * 2);

    auto stageA = [&](int b, int h, int tt) {
        #pragma unroll
        for (int q = 0; q < 2; ++q) {
            const int rit = h * 128 + q * 64 + w * 8 + lr;
            gload_lds16(Agb + (size_t)rit * (DIM * 2) + tt * 128 + csw * 16,
                        &Asm[b][(h * 128 + q * 64 + w * 8) * 128]);
        }
    };
    auto stageB = [&](int b, int h, int tt) {
        #pragma unroll
        for (int q = 0; q < 2; ++q) {
            const int rit = h * 128 + q * 64 + w * 8 + lr;
            gload_lds16(Bgb + (size_t)rit * (DIM * 2) + tt * 128 + csw * 16,
                        &Bsm[b][(h * 128 + q * 64 + w * 8) * 128]);
        }
    };

    auto ldA = [&](bf16x8 (&af)[4][2], int b, int qm) {
        #pragma unroll
        for (int mi = 0; mi < 4; ++mi) {
            const int row = qm * 128 + wm * 64 + mi * 16 + frow;
            const int rsw = (row & 7) << 4;
            #pragma unroll
            for (int k2 = 0; k2 < 2; ++k2)
                af[mi][k2] = *(const bf16x8*)&Asm[b][row * 128 + ((((k2 * 4 + fc) << 4)) ^ rsw)];
        }
    };
    auto ldB = [&](bf16x8 (&bfr)[2][2], int b, int qn) {
        #pragma unroll
        for (int ni = 0; ni < 2; ++ni) {
            const int row = qn * 128 + wn * 32 + ni * 16 + frow;
            const int rsw = (row & 7) << 4;
            #pragma unroll
            for (int k2 = 0; k2 < 2; ++k2)
                bfr[ni][k2] = *(const bf16x8*)&Bsm[b][row * 128 + ((((k2 * 4 + fc) << 4)) ^ rsw)];
        }
    };

    f32x4 acc00[4][2], acc01[4][2], acc11[4][2], acc10[4][2];
    f32x4 zero = {0.f, 0.f, 0.f, 0.f};
    #pragma unroll
    for (int mi = 0; mi < 4; ++mi)
        #pragma unroll
        for (int ni = 0; ni < 2; ++ni) {
            acc00[mi][ni] = zero; acc01[mi][ni] = zero;
            acc11[mi][ni] = zero; acc10[mi][ni] = zero;
        }

    auto mmaq = [&](f32x4 (&ac)[4][2], bf16x8 (&af)[4][2], bf16x8 (&bfr)[2][2]) {
        __builtin_amdgcn_s_setprio(1);
        #pragma unroll
        for (int k2 = 0; k2 < 2; ++k2)
            #pragma unroll
            for (int mi = 0; mi < 4; ++mi)
                #pragma unroll
                for (int ni = 0; ni < 2; ++ni)
                    ac[mi][ni] = __builtin_amdgcn_mfma_f32_16x16x32_bf16(
                        af[mi][k2], bfr[ni][k2], ac[mi][ni], 0, 0, 0);
        __builtin_amdgcn_s_setprio(0);
    };

    #define BAR __builtin_amdgcn_s_barrier()
    #define VM4 asm volatile("s_waitcnt vmcnt(4)" ::: "memory")

    bf16x8 afA[4][2];     // current A-half fragments (A0 in p1-p2, A1 in p3-p4)
    bf16x8 bfr0[2][2];    // B-half0, held p1 -> p4
    bf16x8 bfrB[2][2];    // B-half1

    // ---- prologue: stage K-tile 0 (A0,B0,B1,A1); drain A0,B0 ----
    stageA(0, 0, 0); stageB(0, 0, 0); stageB(0, 1, 0); stageA(0, 1, 0);
    VM4;
    BAR;

    // ---- main loop: tiles t=0..6, staging tile t+1 into buf^1 ----
    #pragma unroll 1
    for (int t = 0; t < 7; ++t) {
        const int b = t & 1, nb = b ^ 1;

        // P1: quadrant (0,0) — 12 ds_reads, stage A0(t+1)
        stageA(nb, 0, t + 1);
        ldA(afA, b, 0);
        ldB(bfr0, b, 0);
        VM4;                            // drains B1(t) (issued 2 phases ago)
        BAR;
        mmaq(acc00, afA, bfr0);
        BAR;

        // P2: quadrant (0,1) — 4 ds_reads, stage B0(t+1)
        stageB(nb, 0, t + 1);
        ldB(bfrB, b, 1);
        VM4;                            // drains A1(t)
        BAR;
        mmaq(acc01, afA, bfrB);
        BAR;

        // P3: quadrant (1,1) — 8 ds_reads, stage B1(t+1)
        stageB(nb, 1, t + 1);
        ldA(afA, b, 1);
        VM4;                            // drains A0(t+1)
        BAR;
        mmaq(acc11, afA, bfrB);
        BAR;

        // P4: quadrant (1,0) — 0 ds_reads (B0 held), stage A1(t+1)
        stageA(nb, 1, t + 1);
        VM4;                            // drains B0(t+1)
        BAR;
        mmaq(acc10, afA, bfr0);
        BAR;
        __builtin_amdgcn_sched_barrier(0);   // window boundary: no cross-window hoists
    }

    // ---- tail: tile 7 in buf 1, no staging; drain 4 -> 2 -> 0 ----
    {
        ldA(afA, 1, 0);
        ldB(bfr0, 1, 0);
        asm volatile("s_waitcnt vmcnt(2)" ::: "memory");   // drains B1(7)
        BAR;
        mmaq(acc00, afA, bfr0);
        BAR;

        ldB(bfrB, 1, 1);
        asm volatile("s_waitcnt vmcnt(0)" ::: "memory");   // drains A1(7)
        BAR;
        mmaq(acc01, afA, bfrB);
        BAR;

        ldA(afA, 1, 1);
        mmaq(acc11, afA, bfrB);
        mmaq(acc10, afA, bfr0);
    }

    // ---- fused epilogue: relu(1 - diag[col] + sc) + relu(1 - diag[row] + sc)
    float lsum = 0.f;
    const int rb0 = bm * 256 + wm * 64;
    const int cb0 = bn * 256 + wn * 32;
    auto sumq = [&](f32x4 (&ac)[4][2], int qm, int qn) {
        #pragma unroll
        for (int mi = 0; mi < 4; ++mi) {
            const int rowb = rb0 + qm * 128 + mi * 16 + fc * 4;
            float dr[4];
            #pragma unroll
            for (int r = 0; r < 4; ++r) dr[r] = diag[rowb + r];
            #pragma unroll
            for (int ni = 0; ni < 2; ++ni) {
                const int col = cb0 + qn * 128 + ni * 16 + frow;
                const float dc = diag[col];
                #pragma unroll
                for (int r = 0; r < 4; ++r) {
                    if (rowb + r != col) {
                        const float sc = ac[mi][ni][r];
                        lsum += fmaxf(0.f, 1.0f - dc + sc)
                              + fmaxf(0.f, 1.0f - dr[r] + sc);
                    }
                }
            }
        }
    };
    sumq(acc00, 0, 0); sumq(acc01, 0, 1); sumq(acc11, 1, 1); sumq(acc10, 1, 0);

    #pragma unroll
    for (int off = 32; off; off >>= 1) lsum += __shfl_down(lsum, off);

    float* part = (float*)&Asm[0][0];   // reuse LDS (all tile reads done)
    __syncthreads();
    if (l == 0) part[w] = lsum;
    __syncthreads();
    if (tid == 0) {
        float bs = 0.f;
        #pragma unroll
        for (int i = 0; i < 8; ++i) bs += part[i];
        atomicAdd(acc_out, (double)bs);
    }
}

__global__ void finalize_kernel(const double* __restrict__ acc, float* __restrict__ out)
{
    out[0] = (float)(acc[0] * (1.0 / (double)NR));
}

extern "C" void kernel_launch(void* const* d_in, const int* in_sizes, int n_in,
                              void* d_out, int out_size, void* d_ws, size_t ws_size,
                              hipStream_t stream)
{
    const float* im = (const float*)d_in[0];
    const float* s  = (const float*)d_in[1];

    char* ws = (char*)d_ws;
    __hip_bfloat16* im_n = (__hip_bfloat16*)ws;                               // 8 MB
    __hip_bfloat16* s_n  = (__hip_bfloat16*)(ws + (size_t)NR * DIM * 2);      // 8 MB
    float* diag          = (float*)(ws + (size_t)NR * DIM * 4);               // 32 KB
    double* acc          = (double*)(ws + (size_t)NR * DIM * 4 + NR * 4);     // 8 B

    normalize_kernel<<<NR, 256, 0, stream>>>(im, s, im_n, s_n, diag, acc);

    dim3 grid(NR / 256, NR / 256);
    gemm_loss_kernel<<<grid, 512, 0, stream>>>(im_n, s_n, diag, acc);

    finalize_kernel<<<1, 1, 0, stream>>>(acc, (float*)d_out);
}